// Round 1
// 790.588 us; speedup vs baseline: 1.0023x; 1.0023x over previous
//
#include <hip/hip_runtime.h>
#include <hip/hip_bf16.h>

// Problem constants (match reference)
#define Bz    4
#define Sz    1024
#define Kz    32
#define Vz    32000
#define MIDz  32
#define MIDDCz 4

// All float tensors are float32 (JAX defaults in the reference; round-1 NaN
// came from misreading them as bf16 -> logf(negative garbage)).
//
// One wave (64 threads) per (b,s) row. Only the returned output knn_prob is
// computed: probs = softmax(-knn_dists*tempe + noise_logit) scattered at
// tgt_index. knn_lambda / sim_lambda / top_k(network_probs) are dead code
// w.r.t. the output, so network_probs (128 MB) and dfc_* are never read.
__global__ __launch_bounds__(64) void combiner_kernel(
    const int*   __restrict__ tgt_index,
    const float* __restrict__ knn_dists,
    const float* __restrict__ knn_key_feature,
    const float* __restrict__ network_select_probs,
    const float* __restrict__ fc1_w1,   // [2,4]
    const float* __restrict__ fc1_b1,   // [4]
    const float* __restrict__ fc1_w2,   // [4,1]
    const float* __restrict__ fc1_b2,   // [1]
    const float* __restrict__ fc2_w1,   // [64,32]
    const float* __restrict__ fc2_b1,   // [32]
    const float* __restrict__ fc2_w2,   // [32,2]
    const float* __restrict__ fc2_b2,   // [2]
    float*       __restrict__ out)      // [B,S,V], pre-zeroed by memset
{
    const int r = blockIdx.x;   // row in [0, B*S)
    const int t = threadIdx.x;  // 0..63

    __shared__ int   idx_s[Kz];
    __shared__ float feat[2 * Kz];   // [knn_dists | label_counts]
    __shared__ float nl_s[Kz];       // noise logits
    __shared__ float h_s[MIDz];      // fc2 hidden
    __shared__ float tempe_s;
    __shared__ float probs_s[Kz];

    const int base = r * Kz;
    float d = 0.f, lkf = 0.f, lsp = 0.f;
    if (t < Kz) {
        idx_s[t] = tgt_index[base + t];
        d   = knn_dists[base + t];
        lkf = logf(knn_key_feature[base + t]);
        lsp = logf(network_select_probs[base + t]);
        feat[t] = d;
    }
    __syncthreads();

    if (t < Kz) {
        // label_counts[t] = # distinct nonzero labels in idx_s[0..t]
        int c = 0;
        for (int j = 0; j <= t; ++j) {
            int vj = idx_s[j];
            if (vj == 0) continue;
            bool first = true;
            for (int j2 = 0; j2 < j; ++j2)
                if (idx_s[j2] == vj) { first = false; break; }
            if (first) ++c;
        }
        feat[Kz + t] = (float)c;

        // noise_logit: [lkf,lsp] -> Linear(2,4) -> tanh -> Linear(4,1)
        float nl = fc1_b2[0];
#pragma unroll
        for (int m = 0; m < MIDDCz; ++m) {
            float hm = tanhf(lkf * fc1_w1[0 * MIDDCz + m] +
                             lsp * fc1_w1[1 * MIDDCz + m] +
                             fc1_b1[m]);
            nl += hm * fc1_w2[m];
        }
        nl_s[t] = nl;
    }
    __syncthreads();

    // fc2: knn_feat(64) -> Linear(64,32) -> tanh ; thread t<32 owns hidden unit t
    if (t < MIDz) {
        float acc = fc2_b1[t];
#pragma unroll
        for (int j = 0; j < 2 * Kz; ++j)
            acc += feat[j] * fc2_w1[j * MIDz + t];
        h_s[t] = tanhf(acc);
    }
    __syncthreads();

    if (t == 0) {
        // only lambda_logit[...,1] (tempe) reaches the output
        float l1 = fc2_b2[1];
        for (int m = 0; m < MIDz; ++m)
            l1 += h_s[m] * fc2_w2[m * 2 + 1];
        tempe_s = 1.f / (1.f + expf(-l1));
    }
    __syncthreads();

    if (t < Kz) {
        const float logit = -d * tempe_s + nl_s[t];
        // softmax over 32 lanes (butterfly partners stay within lanes 0..31)
        float mx = logit;
#pragma unroll
        for (int o = 16; o > 0; o >>= 1)
            mx = fmaxf(mx, __shfl_xor(mx, o, 64));
        float e = expf(logit - mx);
        float sm = e;
#pragma unroll
        for (int o = 16; o > 0; o >>= 1)
            sm += __shfl_xor(sm, o, 64);
        probs_s[t] = e / sm;
    }
    __syncthreads();

    // scatter with in-row dedup: first occurrence of an index accumulates all
    // duplicates in fp32 and does one pure store (addresses distinct within a
    // row; rows own disjoint V-slices -> no atomics needed)
    if (t < Kz) {
        const int myidx = idx_s[t];
        bool first = true;
        for (int j = 0; j < t; ++j)
            if (idx_s[j] == myidx) { first = false; break; }
        if (first) {
            float sum = probs_s[t];
            for (int j = t + 1; j < Kz; ++j)
                if (idx_s[j] == myidx) sum += probs_s[j];
            out[(size_t)r * Vz + myidx] = sum;
        }
    }
}

extern "C" void kernel_launch(void* const* d_in, const int* in_sizes, int n_in,
                              void* d_out, int out_size, void* d_ws, size_t ws_size,
                              hipStream_t stream) {
    const int*   tgt  = (const int*)d_in[0];
    const float* kd   = (const float*)d_in[1];
    const float* kkf  = (const float*)d_in[2];
    // d_in[3] network_probs: dead w.r.t. output — never read
    const float* nsp  = (const float*)d_in[4];
    // d_in[5..6] dfc_w/dfc_b: dead — never read
    const float* f1w1 = (const float*)d_in[7];
    const float* f1b1 = (const float*)d_in[8];
    const float* f1w2 = (const float*)d_in[9];
    const float* f1b2 = (const float*)d_in[10];
    const float* f2w1 = (const float*)d_in[11];
    const float* f2b1 = (const float*)d_in[12];
    const float* f2w2 = (const float*)d_in[13];
    const float* f2b2 = (const float*)d_in[14];
    float*       out  = (float*)d_out;

    // Output is poisoned (0xAA) before every launch: zero exactly the compared
    // region [B,S,V] f32 = 524,288,000 B, then overwrite the <=32 scattered
    // positions per row.
    //
    // ROUND-0 FIX: rocprof showed the previous memset wrote WRITE_SIZE =
    // 2,048,000 KB = 2.097 GB = 4x the output (334 us at 6.27 TB/s) -- out_size
    // is already in BYTES, and the old code multiplied by sizeof(float) again.
    // Hardcoding the true byte count (correct under either convention) cuts the
    // fill to its 524 MB / ~85 us write-BW floor.
    const size_t out_bytes = (size_t)Bz * Sz * Vz * sizeof(float);
    hipMemsetAsync(d_out, 0, out_bytes, stream);
    combiner_kernel<<<Bz * Sz, 64, 0, stream>>>(
        tgt, kd, kkf, nsp, f1w1, f1b1, f1w2, f1b2, f2w1, f2b1, f2w2, f2b2, out);
}